// Round 6
// baseline (54.767 us; speedup 1.0000x reference)
//
#include <hip/hip_runtime.h>

#define Bn 32
#define Nn 256
#define Hn 128
#define En 16
#define WWC 144
#define JT 8            // j-stripes (32 j = 512 floats each)
#define NC 32           // i-chunks of 8 rows (contiguous 128KB slabs)
#define IC 8            // Ppart i-chunks of 32 rows

typedef float v4 __attribute__((ext_vector_type(4)));

// ===== K1: all independent HBM-heavy + prep roles, ONE launch =====
// bid [0,1024): edge colsum, contiguous slabs; [1024,1088): gate; [1088,1344): Ppart; [1344,1408): U_T.
__global__ __launch_bounds__(256) void k_stream(const float* __restrict__ edge, const int* __restrict__ adj,
                                                const float* __restrict__ h, const float* __restrict__ U_w,
                                                float* __restrict__ epart, float* __restrict__ gate,
                                                float* __restrict__ Ppart, float* __restrict__ U_T) {
    int bid = blockIdx.x, t = threadIdx.x;
    __shared__ float red[256];
    if (bid < 1024) {
        // block (b, chunk c): rows c*8 .. c*8+7, ALL 4096 cols -> 128KB contiguous stream
        int b = bid >> 5, c = bid & 31;
        const float* base = edge + ((size_t)b << 20) + ((size_t)c << 15) + t * 4;
        v4 a0 = {0.f,0.f,0.f,0.f}, a1 = a0, a2 = a0, a3 = a0;
        #pragma unroll
        for (int r = 0; r < 8; ++r) {
            const float* rp = base + r * 4096;
            a0 += *reinterpret_cast<const v4*>(rp);
            a1 += *reinterpret_cast<const v4*>(rp + 1024);
            a2 += *reinterpret_cast<const v4*>(rp + 2048);
            a3 += *reinterpret_cast<const v4*>(rp + 3072);
        }
        // thread t, seg s owns col = s*1024 + t*4 -> jt = col>>9, off = col&511
        int off = (t & 127) * 4, hi = t >> 7;
        size_t eb = (((size_t)b * JT) * NC + c) * 512 + off;
        *reinterpret_cast<v4*>(&epart[eb + (size_t)(0 + hi) * (NC * 512)]) = a0;
        *reinterpret_cast<v4*>(&epart[eb + (size_t)(2 + hi) * (NC * 512)]) = a1;
        *reinterpret_cast<v4*>(&epart[eb + (size_t)(4 + hi) * (NC * 512)]) = a2;
        *reinterpret_cast<v4*>(&epart[eb + (size_t)(6 + hi) * (NC * 512)]) = a3;
    } else if (bid < 1088) {
        // gate: 4 i-rows per block, 4KB-contiguous reads per batch
        int i0 = (bid - 1024) * 4;
        int4 s = {0, 0, 0, 0};
        #pragma unroll
        for (int b = 0; b < Bn; ++b) {
            int4 v = *reinterpret_cast<const int4*>(&adj[((size_t)b * Nn + i0) * Nn + t * 4]);
            s.x += v.x; s.y += v.y; s.z += v.z; s.w += v.w;
        }
        v4 g;
        g[0] = s.x > 0 ? 1.f : 0.f; g[1] = s.y > 0 ? 1.f : 0.f;
        g[2] = s.z > 0 ? 1.f : 0.f; g[3] = s.w > 0 ? 1.f : 0.f;
        *reinterpret_cast<v4*>(&gate[i0 * Nn + t * 4]) = g;
    } else if (bid < 1344) {
        int pb = bid - 1088, b = pb >> 3, ic = pb & 7;
        int hh = t & 127, half = t >> 7;
        float s = 0.f;
        #pragma unroll
        for (int k = 0; k < 16; ++k)
            s += h[((size_t)b * Nn + ic * 32 + half * 16 + k) * Hn + hh];
        red[t] = s;
        __syncthreads();
        if (t < 128) Ppart[(ic * Bn + b) * Hn + t] = red[t] + red[t + 128];
    } else {
        int m = (bid - 1344) * 2 + (t >> 7), o = t & 127;
        U_T[m * Hn + o] = U_w[o * Hn + m];
    }
}

// ===== K2: everything dependent, fused. grid (JT, Bn) x 512 =====
__global__ __launch_bounds__(512) void k_final(
    const float* __restrict__ h, const float* __restrict__ U_T, const float* __restrict__ U_b,
    const float* __restrict__ W_w, const float* __restrict__ W_b, const float* __restrict__ gate,
    const float* __restrict__ Ppart, const float* __restrict__ epart, const float* __restrict__ edge,
    const int* __restrict__ num_nodes, float* __restrict__ out) {
    int jt = blockIdx.x, j0 = jt * 32, b = blockIdx.y, t = threadIdx.x;
    __shared__ float shj[Hn][33];
    __shared__ float sgate[Nn][36];
    __shared__ float sWe[Hn][17];
    __shared__ float sE[32][17];
    __shared__ float sP[Hn], sQ[Hn], sWb[Hn], srbuf[Hn], sesub[En], scnt[32];
    __shared__ int szp[16][32];
    __shared__ int szc[32];

    // ---- stage h tile (transposed) ----
    #pragma unroll
    for (int q = 0; q < 2; ++q) {
        int f = t + 512 * q, j = f >> 5, c = f & 31;
        v4 v = *reinterpret_cast<const v4*>(&h[((size_t)b * Nn + j0 + j) * Hn + c * 4]);
        shj[c * 4 + 0][j] = v[0];
        shj[c * 4 + 1][j] = v[1];
        shj[c * 4 + 2][j] = v[2];
        shj[c * 4 + 3][j] = v[3];
    }
    // ---- stage gate tile [256 i][32 j] ----
    #pragma unroll
    for (int q = 0; q < 4; ++q) {
        int f = t + 512 * q, i = f >> 3, c = f & 7;
        *reinterpret_cast<v4*>(&sgate[i][c * 4]) =
            *reinterpret_cast<const v4*>(&gate[i * Nn + j0 + c * 4]);
    }
    {   // We columns of W_w
        int m = t >> 2, c = t & 3;
        v4 v = *reinterpret_cast<const v4*>(&W_w[m * WWC + Hn + c * 4]);
        sWe[m][c * 4 + 0] = v[0];
        sWe[m][c * 4 + 1] = v[1];
        sWe[m][c * 4 + 2] = v[2];
        sWe[m][c * 4 + 3] = v[3];
    }
    if (t < 128) {          // E = reduce epart (contiguous 64KB per block)
        v4 s = {0.f,0.f,0.f,0.f};
        const float* ep = epart + (((size_t)b * JT + jt) * NC) * 512 + t * 4;
        #pragma unroll
        for (int c2 = 0; c2 < NC; ++c2)
            s += *reinterpret_cast<const v4*>(ep + c2 * 512);
        int j = t >> 2, e4 = (t & 3) * 4;
        sE[j][e4 + 0] = s[0]; sE[j][e4 + 1] = s[1]; sE[j][e4 + 2] = s[2]; sE[j][e4 + 3] = s[3];
    } else if (t < 256) {   // P[b,:] = reduce Ppart
        int hh = t - 128;
        float p = 0.f;
        #pragma unroll
        for (int ic = 0; ic < IC; ++ic) p += Ppart[(ic * Bn + b) * Hn + hh];
        sP[hh] = p;
    } else if (t < 384) {
        sWb[t - 256] = W_b[t - 256];
    }
    __syncthreads();

    {   // zero-scan partials: all 512 threads
        int jj = t & 31, grp = t >> 5, zp = 0;
        #pragma unroll
        for (int i = grp; i < Nn; i += 16) zp += (sgate[i][jj] == 0.0f) ? 1 : 0;
        szp[grp][jj] = zp;
    }
    __syncthreads();
    if (t < 32) {
        int zc = 0;
        #pragma unroll
        for (int g2 = 0; g2 < 16; ++g2) zc += szp[g2][t];
        szc[t] = zc;
        scnt[t] = (float)(Nn - zc);
    } else if (t >= 128 && t < 256) {   // Q[b,m] = Wh[m,:]·P[b,:]
        int m = t - 128;
        float s = 0.f;
        #pragma unroll 8
        for (int hh = 0; hh < Hn; ++hh) s += W_w[m * WWC + hh] * sP[hh];
        sQ[m] = s;
    }
    __syncthreads();

    int nn = num_nodes[b];
    // ---- rare exact corrections (gate zeros; normally never taken) ----
    for (int jj = 0; jj < 32; ++jj) {
        if (szc[jj] > 0) {
            if (t < 128) {
                float r = 0.f;
                for (int i = 0; i < Nn; ++i)
                    if (sgate[i][jj] == 0.0f) r += h[((size_t)b * Nn + i) * Hn + t];
                srbuf[t] = r;
            } else if (t < 144) {
                int e = t - 128;
                float r = 0.f;
                for (int i = 0; i < Nn; ++i)
                    if (sgate[i][jj] == 0.0f) r += edge[(((size_t)b * Nn + i) * Nn + j0 + jj) * En + e];
                sesub[e] = r;
            }
            __syncthreads();
            if (t < 128 && (j0 + jj) < nn) {
                float c = 0.f;
                #pragma unroll 8
                for (int hh = 0; hh < Hn; ++hh) c += W_w[t * WWC + hh] * srbuf[hh];
                #pragma unroll
                for (int e = 0; e < En; ++e) c += sWe[t][e] * sesub[e];
                shj[t][jj] -= c;
            }
            __syncthreads();
        }
    }

    // ---- fold y into shj ----
    #pragma unroll
    for (int q = 0; q < 8; ++q) {
        int f = t + 512 * q, m = f >> 5, j = f & 31;
        if (j0 + j < nn) {
            float y = sQ[m] + scnt[j] * sWb[m];
            #pragma unroll
            for (int e = 0; e < En; ++e) y += sWe[m][e] * sE[j][e];
            shj[m][j] += y;
        }
    }
    __syncthreads();

    // ---- GEMV: out = z · U^T + U_b ----
    int og = t & 31, o4 = og * 4, jq = t >> 5, j2 = jq * 2;
    v4 acc0 = {0.f,0.f,0.f,0.f}, acc1 = acc0;
    #pragma unroll 8
    for (int m = 0; m < Hn; ++m) {
        v4 u = *reinterpret_cast<const v4*>(&U_T[m * Hn + o4]);
        acc0 += shj[m][j2] * u;
        acc1 += shj[m][j2 + 1] * u;
    }
    v4 ub = *reinterpret_cast<const v4*>(&U_b[o4]);
    *reinterpret_cast<v4*>(&out[((size_t)b * Nn + j0 + j2) * Hn + o4])     = acc0 + ub;
    *reinterpret_cast<v4*>(&out[((size_t)b * Nn + j0 + j2 + 1) * Hn + o4]) = acc1 + ub;
}

extern "C" void kernel_launch(void* const* d_in, const int* in_sizes, int n_in,
                              void* d_out, int out_size, void* d_ws, size_t ws_size,
                              hipStream_t stream) {
    const float* h    = (const float*)d_in[0];
    const float* edge = (const float*)d_in[1];
    const int*   adj  = (const int*)d_in[2];
    const int*   nn   = (const int*)d_in[3];
    const float* W_w  = (const float*)d_in[4];
    const float* W_b  = (const float*)d_in[5];
    const float* U_w  = (const float*)d_in[6];
    const float* U_b  = (const float*)d_in[7];
    float* out = (float*)d_out;

    float* ws    = (float*)d_ws;
    float* gate  = ws;                  // 65536 floats
    float* Ppart = ws + 65536;          // 32768
    float* U_T   = ws + 98304;          // 16384
    float* epart = ws + 114688;         // 32*8*32*512 = 4194304 floats (16MB)

    hipLaunchKernelGGL(k_stream, dim3(1408),   dim3(256), 0, stream,
                       edge, adj, h, U_w, epart, gate, Ppart, U_T);
    hipLaunchKernelGGL(k_final,  dim3(JT, Bn), dim3(512), 0, stream,
                       h, U_T, U_b, W_w, W_b, gate, Ppart, epart, edge, nn, out);
}

// Round 7
// 51.322 us; speedup vs baseline: 1.0671x; 1.0671x over previous
//
#include <hip/hip_runtime.h>

#define Bn 32
#define Nn 256
#define Hn 128
#define En 16
#define WWC 144
#define JT 8            // j-stripes (32 j = 512 floats each)
#define IC 8            // i-chunks of 32 rows

typedef float v4 __attribute__((ext_vector_type(4)));
typedef int   i4 __attribute__((ext_vector_type(4)));

// ===== K1: all independent HBM-heavy + prep roles, ONE launch =====
// bid [0,2048): edge colsum partials (nt loads); [2048,2112): gate + zero-count atomics;
// [2112,2368): Ppart; [2368,2432): U_T.
__global__ __launch_bounds__(256) void k_stream(const float* __restrict__ edge, const int* __restrict__ adj,
                                                const float* __restrict__ h, const float* __restrict__ U_w,
                                                float* __restrict__ epart, float* __restrict__ gate,
                                                float* __restrict__ Ppart, float* __restrict__ U_T,
                                                int* __restrict__ zcq) {
    int bid = blockIdx.x, t = threadIdx.x;
    if (bid < 2048) {
        // block (b, ic, jt): 32 rows (ic), 512-float j-stripe (jt). 64KB read, 2KB partial out.
        int b = bid >> 6, r = bid & 63, ic = r >> 3, jt = r & 7;
        int ig = t >> 7, vc = t & 127;
        __shared__ v4 sred[128];
        const float* p = edge + ((size_t)b << 20) + (size_t)(ic * 32 + ig) * 4096 + jt * 512 + vc * 4;
        v4 a0 = {0.f,0.f,0.f,0.f}, a1 = a0, a2 = a0, a3 = a0;
        #pragma unroll
        for (int k = 0; k < 16; ++k) {
            v4 v = __builtin_nontemporal_load(reinterpret_cast<const v4*>(p + (size_t)k * 8192));
            if ((k & 3) == 0) a0 += v; else if ((k & 3) == 1) a1 += v;
            else if ((k & 3) == 2) a2 += v; else a3 += v;
        }
        v4 s = (a0 + a1) + (a2 + a3);
        if (ig == 1) sred[vc] = s;
        __syncthreads();
        if (ig == 0) {
            s += sred[vc];
            *reinterpret_cast<v4*>(&epart[(((size_t)b * JT + jt) * IC + ic) * 512 + vc * 4]) = s;
        }
    } else if (bid < 2112) {
        // gate: 4 flattened i-rows per block; nt int4 loads; integer zero-count atomics (normally none fire)
        int f0 = (bid - 2048) * 1024;      // flat index into [256][256]
        i4 s = {0, 0, 0, 0};
        #pragma unroll
        for (int b = 0; b < Bn; ++b)
            s += __builtin_nontemporal_load(reinterpret_cast<const i4*>(&adj[(size_t)b * (Nn * Nn) + f0 + t * 4]));
        v4 g;
        g[0] = s[0] > 0 ? 1.f : 0.f; g[1] = s[1] > 0 ? 1.f : 0.f;
        g[2] = s[2] > 0 ? 1.f : 0.f; g[3] = s[3] > 0 ? 1.f : 0.f;
        *reinterpret_cast<v4*>(&gate[f0 + t * 4]) = g;
        __shared__ int szl[4][Nn];
        int rr = t >> 6, c4 = (t & 63) * 4;
        szl[rr][c4 + 0] = (s[0] == 0);
        szl[rr][c4 + 1] = (s[1] == 0);
        szl[rr][c4 + 2] = (s[2] == 0);
        szl[rr][c4 + 3] = (s[3] == 0);
        __syncthreads();
        int zs = szl[0][t] + szl[1][t] + szl[2][t] + szl[3][t];
        if (zs > 0) atomicAdd(&zcq[t], zs);   // int atomic: order-independent, deterministic
    } else if (bid < 2368) {
        int pb = bid - 2112, b = pb >> 3, ic = pb & 7;
        int hh = t & 127, half = t >> 7;
        __shared__ float red[256];
        float s = 0.f;
        #pragma unroll
        for (int k = 0; k < 16; ++k)
            s += h[((size_t)b * Nn + ic * 32 + half * 16 + k) * Hn + hh];
        red[t] = s;
        __syncthreads();
        if (t < 128) Ppart[(ic * Bn + b) * Hn + t] = red[t] + red[t + 128];
    } else {
        int m = (bid - 2368) * 2 + (t >> 7), o = t & 127;
        U_T[m * Hn + o] = U_w[o * Hn + m];
    }
}

// ===== K2: everything dependent, fused. grid (JT, Bn) x 512 =====
__global__ __launch_bounds__(512) void k_final(
    const float* __restrict__ h, const float* __restrict__ U_T, const float* __restrict__ U_b,
    const float* __restrict__ W_w, const float* __restrict__ W_b, const float* __restrict__ gate,
    const float* __restrict__ Ppart, const float* __restrict__ epart, const float* __restrict__ edge,
    const int* __restrict__ zcq, const int* __restrict__ num_nodes, float* __restrict__ out) {
    int jt = blockIdx.x, j0 = jt * 32, b = blockIdx.y, t = threadIdx.x;
    __shared__ float shj[Hn][33];
    __shared__ float sWe[Hn][17];
    __shared__ float sE[32][17];
    __shared__ float sqp[Hn][4];
    __shared__ float sP[Hn], sQ[Hn], sWb[Hn], srbuf[Hn], sesub[En], scnt[32];

    // ---- stage h tile (transposed) ----
    #pragma unroll
    for (int q = 0; q < 2; ++q) {
        int f = t + 512 * q, j = f >> 5, c = f & 31;
        v4 v = *reinterpret_cast<const v4*>(&h[((size_t)b * Nn + j0 + j) * Hn + c * 4]);
        shj[c * 4 + 0][j] = v[0];
        shj[c * 4 + 1][j] = v[1];
        shj[c * 4 + 2][j] = v[2];
        shj[c * 4 + 3][j] = v[3];
    }
    {   // We columns of W_w
        int m = t >> 2, c = t & 3;
        v4 v = *reinterpret_cast<const v4*>(&W_w[m * WWC + Hn + c * 4]);
        sWe[m][c * 4 + 0] = v[0];
        sWe[m][c * 4 + 1] = v[1];
        sWe[m][c * 4 + 2] = v[2];
        sWe[m][c * 4 + 3] = v[3];
    }
    if (t < 128) {          // E = reduce epart (contiguous 16KB per block)
        const float* ep = epart + (((size_t)b * JT + jt) * IC) * 512 + t * 4;
        v4 s = {0.f,0.f,0.f,0.f};
        #pragma unroll
        for (int ic = 0; ic < IC; ++ic)
            s += *reinterpret_cast<const v4*>(ep + ic * 512);
        int j = t >> 2, e4 = (t & 3) * 4;
        sE[j][e4 + 0] = s[0]; sE[j][e4 + 1] = s[1]; sE[j][e4 + 2] = s[2]; sE[j][e4 + 3] = s[3];
    } else if (t < 256) {   // P[b,:] = reduce Ppart
        int hh = t - 128;
        float p = 0.f;
        #pragma unroll
        for (int ic = 0; ic < IC; ++ic) p += Ppart[(ic * Bn + b) * Hn + hh];
        sP[hh] = p;
    } else if (t < 384) {
        sWb[t - 256] = W_b[t - 256];
    } else if (t < 416) {
        scnt[t - 384] = (float)(Nn - zcq[j0 + t - 384]);
    }
    __syncthreads();

    {   // Q[b,m] = Wh[m,:]·P[b,:] : 4 threads per m
        int m = t >> 2, q = t & 3;
        const v4* wp = reinterpret_cast<const v4*>(&W_w[m * WWC + q * 32]);
        const v4* pp = reinterpret_cast<const v4*>(&sP[q * 32]);
        v4 sv = {0.f,0.f,0.f,0.f};
        #pragma unroll
        for (int k = 0; k < 8; ++k) sv += wp[k] * pp[k];
        sqp[m][q] = (sv[0] + sv[1]) + (sv[2] + sv[3]);
    }
    __syncthreads();
    if (t < 128) sQ[t] = (sqp[t][0] + sqp[t][1]) + (sqp[t][2] + sqp[t][3]);
    __syncthreads();

    int nn = num_nodes[b];
    // ---- rare exact corrections (gate zeros; normally never taken) ----
    for (int jj = 0; jj < 32; ++jj) {
        if (scnt[jj] < 255.5f) {
            if (t < 128) {
                float r = 0.f;
                for (int i = 0; i < Nn; ++i)
                    if (gate[i * Nn + j0 + jj] == 0.0f) r += h[((size_t)b * Nn + i) * Hn + t];
                srbuf[t] = r;
            } else if (t < 144) {
                int e = t - 128;
                float r = 0.f;
                for (int i = 0; i < Nn; ++i)
                    if (gate[i * Nn + j0 + jj] == 0.0f)
                        r += edge[(((size_t)b * Nn + i) * Nn + j0 + jj) * En + e];
                sesub[e] = r;
            }
            __syncthreads();
            if (t < 128 && (j0 + jj) < nn) {
                float c = 0.f;
                #pragma unroll 8
                for (int hh = 0; hh < Hn; ++hh) c += W_w[t * WWC + hh] * srbuf[hh];
                #pragma unroll
                for (int e = 0; e < En; ++e) c += sWe[t][e] * sesub[e];
                shj[t][jj] -= c;
            }
            __syncthreads();
        }
    }

    // ---- fold y into shj ----
    #pragma unroll
    for (int q = 0; q < 8; ++q) {
        int f = t + 512 * q, m = f >> 5, j = f & 31;
        if (j0 + j < nn) {
            float y = sQ[m] + scnt[j] * sWb[m];
            #pragma unroll
            for (int e = 0; e < En; ++e) y += sWe[m][e] * sE[j][e];
            shj[m][j] += y;
        }
    }
    __syncthreads();

    // ---- GEMV: out = z · U^T + U_b ----
    int og = t & 31, o4 = og * 4, jq = t >> 5, j2 = jq * 2;
    v4 acc0 = {0.f,0.f,0.f,0.f}, acc1 = acc0;
    #pragma unroll 8
    for (int m = 0; m < Hn; ++m) {
        v4 u = *reinterpret_cast<const v4*>(&U_T[m * Hn + o4]);
        acc0 += shj[m][j2] * u;
        acc1 += shj[m][j2 + 1] * u;
    }
    v4 ub = *reinterpret_cast<const v4*>(&U_b[o4]);
    __builtin_nontemporal_store(acc0 + ub,
        reinterpret_cast<v4*>(&out[((size_t)b * Nn + j0 + j2) * Hn + o4]));
    __builtin_nontemporal_store(acc1 + ub,
        reinterpret_cast<v4*>(&out[((size_t)b * Nn + j0 + j2 + 1) * Hn + o4]));
}

extern "C" void kernel_launch(void* const* d_in, const int* in_sizes, int n_in,
                              void* d_out, int out_size, void* d_ws, size_t ws_size,
                              hipStream_t stream) {
    const float* h    = (const float*)d_in[0];
    const float* edge = (const float*)d_in[1];
    const int*   adj  = (const int*)d_in[2];
    const int*   nn   = (const int*)d_in[3];
    const float* W_w  = (const float*)d_in[4];
    const float* W_b  = (const float*)d_in[5];
    const float* U_w  = (const float*)d_in[6];
    const float* U_b  = (const float*)d_in[7];
    float* out = (float*)d_out;

    float* ws    = (float*)d_ws;
    float* gate  = ws;                  // 65536 floats
    float* Ppart = ws + 65536;          // 32768
    float* U_T   = ws + 98304;          // 16384
    float* epart = ws + 114688;         // 1048576 floats (4MB)
    int*   zcq   = (int*)(ws + 114688 + 1048576);  // 256 ints

    hipMemsetAsync(zcq, 0, Nn * sizeof(int), stream);
    hipLaunchKernelGGL(k_stream, dim3(2432),   dim3(256), 0, stream,
                       edge, adj, h, U_w, epart, gate, Ppart, U_T, zcq);
    hipLaunchKernelGGL(k_final,  dim3(JT, Bn), dim3(512), 0, stream,
                       h, U_T, U_b, W_w, W_b, gate, Ppart, epart, edge, zcq, nn, out);
}